// Round 2
// baseline (1751.426 us; speedup 1.0000x reference)
//
#include <hip/hip_runtime.h>

#define BB 256
#define TT 2048
#define NN 64

__global__ __launch_bounds__(64, 1)
void crf_viterbi_kernel(const float* __restrict__ x,
                        const int* __restrict__ seq_len,
                        const float* __restrict__ trans,
                        float* __restrict__ out) {
  const int b = blockIdx.x;
  const int j = threadIdx.x;  // 0..63, one lane per state

  __shared__ __align__(16) float alpha_s[2][NN];
  __shared__ unsigned char bp_s[(TT - 1) * NN];  // 131008 B backpointers
  __shared__ int s_last;
  __shared__ float s_best;

  const float* xb = x + (size_t)b * TT * NN;
  const int slen = seq_len[b];

  // trans column j -> registers (coalesced: for fixed i, lanes j contiguous)
  float tc[NN];
#pragma unroll
  for (int i = 0; i < NN; ++i) tc[i] = trans[i * NN + j];

  // alpha0 = x[:,0]
  alpha_s[0][j] = xb[j];
  __syncthreads();

  int cur = 0;
  float xnext = (slen > 1) ? xb[NN + j] : 0.0f;  // prefetch x_t one step ahead

  for (int t = 1; t < slen; ++t) {
    float xv = xnext;
    if (t + 1 < slen) xnext = xb[(size_t)(t + 1) * NN + j];

    float m = -INFINITY;
    int bp = 0;
#pragma unroll
    for (int k = 0; k < 16; ++k) {
      float4 a4 = *reinterpret_cast<const float4*>(&alpha_s[cur][4 * k]);
      float c;
      bool g;
      c = a4.x + tc[4 * k + 0]; g = c > m; m = g ? c : m; bp = g ? 4 * k + 0 : bp;
      c = a4.y + tc[4 * k + 1]; g = c > m; m = g ? c : m; bp = g ? 4 * k + 1 : bp;
      c = a4.z + tc[4 * k + 2]; g = c > m; m = g ? c : m; bp = g ? 4 * k + 2 : bp;
      c = a4.w + tc[4 * k + 3]; g = c > m; m = g ? c : m; bp = g ? 4 * k + 3 : bp;
    }

    alpha_s[cur ^ 1][j] = m + xv;
    bp_s[(t - 1) * NN + j] = (unsigned char)bp;
    __syncthreads();  // single-wave barrier: orders LDS write -> next-step reads
    cur ^= 1;
  }

  // final max/argmax over states (first-occurrence tie-break, matches jnp.argmax)
  if (j == 0) {
    float best = alpha_s[cur][0];
    int bi = 0;
    for (int i = 1; i < NN; ++i) {
      float v = alpha_s[cur][i];
      if (v > best) { best = v; bi = i; }
    }
    s_last = bi;
    s_best = best;
  }
  __syncthreads();
  const int last = s_last;
  const float lastf = (float)last;

  // tags[t] = last for all t >= slen-1 (identity backpointers), coalesced
  for (int t = slen - 1 + j; t < TT; t += NN) out[b * TT + t] = lastf;

  if (j == 0) {
    // scores: exact fp32 value (whole d_out is float32)
    out[BB * TT + b] = s_best;

    // traceback: tags[t] = bp_{t+1}[tags[t+1]], bp_{t+1} stored at LDS row t
    int tag = last;
    for (int t = slen - 2; t >= 0; --t) {
      tag = bp_s[t * NN + tag];
      out[b * TT + t] = (float)tag;
    }
  }
}

extern "C" void kernel_launch(void* const* d_in, const int* in_sizes, int n_in,
                              void* d_out, int out_size, void* d_ws, size_t ws_size,
                              hipStream_t stream) {
  const float* x = (const float*)d_in[0];
  const int* seq_len = (const int*)d_in[1];
  const float* trans = (const float*)d_in[2];
  float* out = (float*)d_out;

  crf_viterbi_kernel<<<BB, 64, 0, stream>>>(x, seq_len, trans, out);
}